// Round 3
// baseline (3302.434 us; speedup 1.0000x reference)
//
#include <hip/hip_runtime.h>
#include <math.h>

// CRITICAL: no FMA contraction anywhere — we are bit-replicating numpy's
// SSE (no-FMA) float32 einsum inner loop.
#pragma clang fp contract(off)

#define T_TOKENS 16384
#define HDIM 2048
#define NEXP 64
#define TOPK 6
#define SEQ 4096
#define TPB 32          // tokens per block
#define KC 64           // k-chunk
#define NC (HDIM / KC)  // 32 chunks
#define WS 68           // padded LDS stride for W tile
#define XS 68           // padded LDS stride for X tile
#define LGS 65          // padded stride for logits
#define PS 65           // padded stride for probs

// numpy einsum contig_two micro-step (SSE3 baseline, 4 lanes, no FMA):
// per 16-element block: vacc[l] = a0[l]*b0[l] + (a1[l]*b1[l] + (a2[l]*b2[l] + (a3[l]*b3[l] + vacc[l])))
__device__ __forceinline__ void np_upd(const float4& w0, const float4& w1,
                                       const float4& w2, const float4& w3,
                                       const float4& x0, const float4& x1,
                                       const float4& x2, const float4& x3,
                                       float acc[4])
{
    acc[0] = w0.x*x0.x + (w1.x*x1.x + (w2.x*x2.x + (w3.x*x3.x + acc[0])));
    acc[1] = w0.y*x0.y + (w1.y*x1.y + (w2.y*x2.y + (w3.y*x3.y + acc[1])));
    acc[2] = w0.z*x0.z + (w1.z*x1.z + (w2.z*x2.z + (w3.z*x3.z + acc[2])));
    acc[3] = w0.w*x0.w + (w1.w*x1.w + (w2.w*x2.w + (w3.w*x3.w + acc[3])));
}

// 512 threads = 8 waves; each thread: 1 token row x 4 experts.
// Grid 512 blocks -> 2 blocks/CU, 16 waves/CU (4 waves/SIMD).
// Double-buffered LDS staging: loads for chunk c+1 issue BEFORE compute of
// chunk c; the vmcnt drain + ds_write + single barrier land AFTER compute,
// so global latency hides under the 4x b16 compute phase.
__global__ __launch_bounds__(512, 4) void moe_gate_main(
    const float* __restrict__ x, const float* __restrict__ wgt,
    float* __restrict__ out, float* __restrict__ gacc)
{
    __shared__ float w_lds[2][NEXP * WS];  // 34816 B
    __shared__ float x_lds[2][TPB * XS];   // 17408 B
    __shared__ float lg[TPB * LGS];        //  8320 B  fp32 logits (np bit-exact)
    __shared__ float probs[TPB * PS];      //  8320 B
    __shared__ float psum[8 * NEXP];       //  2048 B
    __shared__ int   cnt[NEXP];            //   256 B   (~71 KB total, 2 blocks/CU)

    const int tid  = threadIdx.x;
    const int bid  = blockIdx.x;
    const int tb   = bid * TPB;
    const int b    = tb / SEQ;

    const int lane = tid & 63;
    const int wv   = tid >> 6;       // 0..7
    const int le   = lane & 15;      // expert sub-index
    const int g    = lane >> 4;      // 0..3
    const int trow = wv * 4 + g;     // token row 0..31

    // ---- staging geometry (fixed per thread; only k0 varies per chunk)
    const int we = tid >> 4;         // W expert row, round 0 (0..31); round 1 = we+32
    const int wc = tid & 15;         // 16B slot within row
    const int xt = tid >> 4;         // X token row (0..31)
    const int xc = tid & 15;
    const float* wg0 = &wgt[(size_t)we * HDIM + wc * 4];
    const float* wg1 = &wgt[(size_t)(we + 32) * HDIM + wc * 4];
    const float* xg  = &x[(size_t)(tb + xt) * HDIM + xc * 4];
    const int wl0 = we * WS + wc * 4;
    const int wl1 = (we + 32) * WS + wc * 4;
    const int xl  = xt * XS + xc * 4;

    // acc[expert_j][simd_lane]
    float acc[4][4];
    #pragma unroll
    for (int j = 0; j < 4; ++j)
        #pragma unroll
        for (int l = 0; l < 4; ++l) acc[j][l] = 0.f;

    // ---- prologue: stage chunk 0 into buffer 0
    float4 wt0 = *reinterpret_cast<const float4*>(wg0);
    float4 wt1 = *reinterpret_cast<const float4*>(wg1);
    float4 xt0 = *reinterpret_cast<const float4*>(xg);
    *reinterpret_cast<float4*>(&w_lds[0][wl0]) = wt0;
    *reinterpret_cast<float4*>(&w_lds[0][wl1]) = wt1;
    *reinterpret_cast<float4*>(&x_lds[0][xl])  = xt0;
    __syncthreads();

    #pragma unroll 1
    for (int c = 0; c < NC; ++c) {
        const int cur = c & 1;
        // issue next chunk's loads (stay in flight under compute)
        if (c + 1 < NC) {
            const int k1 = (c + 1) * KC;
            wt0 = *reinterpret_cast<const float4*>(wg0 + k1);
            wt1 = *reinterpret_cast<const float4*>(wg1 + k1);
            xt0 = *reinterpret_cast<const float4*>(xg + k1);
        }

        // ---- compute chunk c from buf[cur]; k ascending in blocks of 16
        const float* wb = &w_lds[cur][0];
        const float* xb = &x_lds[cur][0];
        #pragma unroll
        for (int b16 = 0; b16 < 4; ++b16) {
            const int kb = b16 * 16;
            float4 xa[4];
            #pragma unroll
            for (int j = 0; j < 4; ++j)
                xa[j] = *reinterpret_cast<const float4*>(&xb[trow * XS + kb + j * 4]);
            #pragma unroll
            for (int je = 0; je < 4; ++je) {
                const float* wr = &wb[(le + 16 * je) * WS + kb];
                float4 w0 = *reinterpret_cast<const float4*>(wr);
                float4 w1 = *reinterpret_cast<const float4*>(wr + 4);
                float4 w2 = *reinterpret_cast<const float4*>(wr + 8);
                float4 w3 = *reinterpret_cast<const float4*>(wr + 12);
                np_upd(w0, w1, w2, w3, xa[0], xa[1], xa[2], xa[3], acc[je]);
            }
        }

        // ---- write chunk c+1 into the other buffer; one barrier per chunk
        if (c + 1 < NC) {
            const int nxt = cur ^ 1;
            *reinterpret_cast<float4*>(&w_lds[nxt][wl0]) = wt0;
            *reinterpret_cast<float4*>(&w_lds[nxt][wl1]) = wt1;
            *reinterpret_cast<float4*>(&x_lds[nxt][xl])  = xt0;
            __syncthreads();
        }
    }

    // horizontal reduce exactly like npyv_sum_f32 (SSE3 hadd): (v0+v1)+(v2+v3)
    #pragma unroll
    for (int je = 0; je < 4; ++je) {
        float v = (acc[je][0] + acc[je][1]) + (acc[je][2] + acc[je][3]);
        lg[trow * LGS + le + 16 * je] = v;
    }
    if (tid < NEXP) cnt[tid] = 0;
    __syncthreads();

    // ---- softmax per token (threads 0..31), fp32 like np
    if (tid < TPB) {
        const int t = tid;
        float mx = lg[t * LGS];
        for (int e = 1; e < NEXP; ++e) { float v = lg[t * LGS + e]; if (v > mx) mx = v; }
        for (int e = 0; e < NEXP; ++e)
            probs[t * PS + e] = expf(lg[t * LGS + e] - mx);
        // numpy pairwise sum, n=64: 8 strided accumulators then paired combine
        float r[8];
        #pragma unroll
        for (int j = 0; j < 8; ++j) r[j] = probs[t * PS + j];
        for (int i = 8; i < 64; i += 8)
            #pragma unroll
            for (int j = 0; j < 8; ++j) r[j] += probs[t * PS + i + j];
        float S = ((r[0] + r[1]) + (r[2] + r[3])) + ((r[4] + r[5]) + (r[6] + r[7]));
        for (int e = 0; e < NEXP; ++e) probs[t * PS + e] = probs[t * PS + e] / S;
    }
    __syncthreads();

    // ---- partial per-expert score sums (aux loss), all 512 threads
    {
        const int e = tid & 63, q = tid >> 6;   // q = 0..7, 4 tokens each
        float s = 0.f;
        for (int t = q * 4; t < q * 4 + 4; ++t) s += probs[t * PS + e];
        psum[q * 64 + e] = s;
    }
    __syncthreads();

    if (tid < TPB) {
        // ---- top-6 on fp32 probs, strict > ascending scan (tie -> lowest index)
        const int t = tid;
        const int gt = tb + t;
        float pv[TOPK]; int pi[TOPK];
        for (int r = 0; r < TOPK; ++r) {
            float bv = -1.f; int be = 0;
            for (int e = 0; e < NEXP; ++e) {
                float v = probs[t * PS + e];
                if (v > bv) { bv = v; be = e; }
            }
            probs[t * PS + be] = -1.f;
            pv[r] = bv; pi[r] = be;
            atomicAdd(&cnt[be], 1);
        }
        float wsum = pv[0];
        #pragma unroll
        for (int r = 1; r < TOPK; ++r) wsum += pv[r];
        wsum += 1e-20f;
        #pragma unroll
        for (int r = 0; r < TOPK; ++r) {
            out[(size_t)gt * TOPK + r] = (float)pi[r];
            out[(size_t)T_TOKENS * TOPK + (size_t)gt * TOPK + r] = pv[r] / wsum;
        }
    } else if (tid >= 64 && tid < 128) {
        const int e = tid - 64;
        float s = 0.f;
        #pragma unroll
        for (int q = 0; q < 8; ++q) s += psum[q * 64 + e];
        atomicAdd(&gacc[b * 64 + e], s);
    }
    __syncthreads();
    if (tid < NEXP) {
        atomicAdd(&gacc[256 + b * 64 + tid], (float)cnt[tid]);
    }
}

__global__ __launch_bounds__(256) void moe_gate_aux(
    const float* __restrict__ gacc, float* __restrict__ out)
{
    __shared__ float red[4];
    const int tid = threadIdx.x;
    float v = gacc[256 + tid] * gacc[tid];
    #pragma unroll
    for (int o = 32; o > 0; o >>= 1) v += __shfl_down(v, o, 64);
    if ((tid & 63) == 0) red[tid >> 6] = v;
    __syncthreads();
    if (tid == 0) {
        float tot = red[0] + red[1] + red[2] + red[3];
        const float scale = (64.0f / (4096.0f * 6.0f)) / 4096.0f;
        out[2 * T_TOKENS * TOPK] = 1e-3f * (tot * scale) * 0.25f;
    }
}

extern "C" void kernel_launch(void* const* d_in, const int* in_sizes, int n_in,
                              void* d_out, int out_size, void* d_ws, size_t ws_size,
                              hipStream_t stream) {
    const float* x   = (const float*)d_in[0];
    const float* wgt = (const float*)d_in[1];
    float* out  = (float*)d_out;
    float* gacc = (float*)d_ws;

    hipMemsetAsync(d_ws, 0, 512 * sizeof(float), stream);
    moe_gate_main<<<T_TOKENS / TPB, 512, 0, stream>>>(x, wgt, out, gacc);
    moe_gate_aux<<<1, 256, 0, stream>>>(gacc, out);
}

// Round 5
// 388.047 us; speedup vs baseline: 8.5104x; 8.5104x over previous
//
#include <hip/hip_runtime.h>
#include <math.h>

// CRITICAL: no FMA contraction anywhere — we are bit-replicating numpy's
// SSE (no-FMA) float32 einsum inner loop.
#pragma clang fp contract(off)

#define T_TOKENS 16384
#define HDIM 2048
#define NEXP 64
#define TOPK 6
#define SEQ 4096
#define TPB 64              // tokens per block (= lanes of a wave)
#define KC 64               // k-chunk (floats)
#define NC (HDIM / KC)      // 32 chunks
#define LGS 65              // padded stride for logits
#define PS 65               // padded stride for probs

typedef __attribute__((ext_vector_type(16))) float f32x16;
typedef __attribute__((address_space(1))) const unsigned int gu32;
typedef __attribute__((address_space(3))) unsigned int lu32;

// numpy einsum contig_two micro-step (SSE3 baseline, 4 lanes, no FMA), with the
// 16 W floats passed as a (wave-uniform, SGPR-resident) 16-vector.
// w[0..3]=w0, w[4..7]=w1, w[8..11]=w2, w[12..15]=w3 — identical FP order to np_upd.
__device__ __forceinline__ void np_upd16(const f32x16 w,
                                         const float4& x0, const float4& x1,
                                         const float4& x2, const float4& x3,
                                         float acc[4])
{
    acc[0] = w[0]*x0.x + (w[4]*x1.x + (w[8]*x2.x  + (w[12]*x3.x + acc[0])));
    acc[1] = w[1]*x0.y + (w[5]*x1.y + (w[9]*x2.y  + (w[13]*x3.y + acc[1])));
    acc[2] = w[2]*x0.z + (w[6]*x1.z + (w[10]*x2.z + (w[14]*x3.z + acc[2])));
    acc[3] = w[3]*x0.w + (w[7]*x1.w + (w[11]*x2.w + (w[15]*x3.w + acc[3])));
}

// 1024 threads = 16 waves. lane = token (64 tokens/block); wave = 4 experts.
// W is read through wave-uniform (scalar s_load) addresses — zero LDS, zero VGPR.
// X staged global->LDS via global_load_lds (no VGPR round-trip, no spill risk),
// double-buffered, XOR-swizzled (phys 16B slot = logical ^ (row&7)) so the
// 64-lane own-row ds_read_b128 is bank-balanced (8 dwords/bank, the minimum).
__global__ __launch_bounds__(1024, 4) void moe_gate_main(
    const float* __restrict__ x, const float* __restrict__ wgt,
    float* __restrict__ out, float* __restrict__ gacc)
{
    __shared__ __attribute__((aligned(16))) float xs[2 * TPB * KC];  // 32 KB
    __shared__ float lg[TPB * LGS];        // 16640 B fp32 logits (np bit-exact)
    __shared__ float probs[TPB * PS];      // 16640 B
    __shared__ float psum[16 * NEXP];      //  4096 B
    __shared__ int   cnt[NEXP];            //   256 B   (~70 KB total)

    const int tid  = threadIdx.x;
    const int bid  = blockIdx.x;
    const int tb   = bid * TPB;
    const int b    = bid >> 6;             // 64 blocks per batch row

    const int lane = tid & 63;             // token row
    const int e0   = __builtin_amdgcn_readfirstlane(tid >> 6) * 4;  // wave's experts e0..e0+3

    // ---- staging geometry: 1024 threads x one 16B slot per chunk.
    // phys slot index i=tid -> (row=i>>4, p=i&15); holds logical slot s = p ^ (row&7).
    const int srow = tid >> 4;
    const int ss   = (tid & 15) ^ (srow & 7);
    const float* xsrc = x + (size_t)(tb + srow) * HDIM + ss * 4;
    char* ldst = (char*)xs + tid * 16;     // wave-uniform base + lane*16 (m97 pattern)

    float acc[4][4];
    #pragma unroll
    for (int j = 0; j < 4; ++j)
        #pragma unroll
        for (int l = 0; l < 4; ++l) acc[j][l] = 0.f;

    // ---- prologue: stage chunk 0 into buffer 0 (async, reg-free)
    __builtin_amdgcn_global_load_lds((gu32*)xsrc, (lu32*)ldst, 16, 0, 0);
    __syncthreads();                       // compiler drains vmcnt before barrier

    const char* xrow = (const char*)xs + lane * (KC * 4);  // own token row, buffer 0
    const int   swz  = lane & 7;           // read-side slot XOR

    for (int c = 0; c < NC; ++c) {
        const int cur = c & 1;
        // issue next chunk's staging (stays in flight under compute; drained
        // by the compiler's vmcnt(0) at the end-of-iteration barrier)
        if (c + 1 < NC)
            __builtin_amdgcn_global_load_lds((gu32*)(xsrc + (c + 1) * KC),
                                             (lu32*)(ldst + ((cur ^ 1) * TPB * KC * 4)),
                                             16, 0, 0);

        const char* xb = xrow + cur * (TPB * KC * 4);
        const float* wc = wgt + (size_t)e0 * HDIM + c * KC;   // wave-uniform
        #pragma unroll
        for (int b16 = 0; b16 < 4; ++b16) {
            // own token row: 16 floats (4 swizzled b128 reads), reused across 4 experts
            const float4 xa0 = *(const float4*)(xb + (((b16 * 4 + 0) ^ swz) << 4));
            const float4 xa1 = *(const float4*)(xb + (((b16 * 4 + 1) ^ swz) << 4));
            const float4 xa2 = *(const float4*)(xb + (((b16 * 4 + 2) ^ swz) << 4));
            const float4 xa3 = *(const float4*)(xb + (((b16 * 4 + 3) ^ swz) << 4));
            #pragma unroll
            for (int je = 0; je < 4; ++je) {
                const f32x16 w = *reinterpret_cast<const f32x16*>(
                    wc + (size_t)je * HDIM + b16 * 16);       // uniform -> s_load_dwordx16
                np_upd16(w, xa0, xa1, xa2, xa3, acc[je]);
            }
        }
        __syncthreads();
    }

    // horizontal reduce exactly like npyv_sum_f32 (SSE3 hadd): (v0+v1)+(v2+v3)
    #pragma unroll
    for (int je = 0; je < 4; ++je) {
        float v = (acc[je][0] + acc[je][1]) + (acc[je][2] + acc[je][3]);
        lg[lane * LGS + e0 + je] = v;
    }
    if (tid < NEXP) cnt[tid] = 0;
    __syncthreads();

    // ---- softmax per token (threads 0..63), fp32 like np
    if (tid < TPB) {
        const int t = tid;
        float mx = lg[t * LGS];
        for (int e = 1; e < NEXP; ++e) { float v = lg[t * LGS + e]; if (v > mx) mx = v; }
        for (int e = 0; e < NEXP; ++e)
            probs[t * PS + e] = expf(lg[t * LGS + e] - mx);
        // numpy pairwise sum, n=64: 8 strided accumulators then paired combine
        float r[8];
        #pragma unroll
        for (int j = 0; j < 8; ++j) r[j] = probs[t * PS + j];
        for (int i = 8; i < 64; i += 8)
            #pragma unroll
            for (int j = 0; j < 8; ++j) r[j] += probs[t * PS + i + j];
        float S = ((r[0] + r[1]) + (r[2] + r[3])) + ((r[4] + r[5]) + (r[6] + r[7]));
        for (int e = 0; e < NEXP; ++e) probs[t * PS + e] = probs[t * PS + e] / S;
    }
    __syncthreads();

    // ---- partial per-expert score sums (aux loss), all 1024 threads
    {
        const int e = tid & 63, q = tid >> 6;   // q = 0..15, 4 tokens each
        float s = 0.f;
        for (int t = q * 4; t < q * 4 + 4; ++t) s += probs[t * PS + e];
        psum[q * 64 + e] = s;
    }
    __syncthreads();

    if (tid < TPB) {
        // ---- top-6 on fp32 probs, strict > ascending scan (tie -> lowest index)
        const int t = tid;
        const int gt = tb + t;
        float pv[TOPK]; int pi[TOPK];
        for (int r = 0; r < TOPK; ++r) {
            float bv = -1.f; int be = 0;
            for (int e = 0; e < NEXP; ++e) {
                float v = probs[t * PS + e];
                if (v > bv) { bv = v; be = e; }
            }
            probs[t * PS + be] = -1.f;
            pv[r] = bv; pi[r] = be;
            atomicAdd(&cnt[be], 1);
        }
        float wsum = pv[0];
        #pragma unroll
        for (int r = 1; r < TOPK; ++r) wsum += pv[r];
        wsum += 1e-20f;
        #pragma unroll
        for (int r = 0; r < TOPK; ++r) {
            out[(size_t)gt * TOPK + r] = (float)pi[r];
            out[(size_t)T_TOKENS * TOPK + (size_t)gt * TOPK + r] = pv[r] / wsum;
        }
    } else if (tid >= 64 && tid < 128) {
        const int e = tid - 64;
        float s = 0.f;
        #pragma unroll
        for (int q = 0; q < 16; ++q) s += psum[q * 64 + e];
        atomicAdd(&gacc[b * 64 + e], s);
    }
    __syncthreads();
    if (tid < NEXP) {
        atomicAdd(&gacc[256 + b * 64 + tid], (float)cnt[tid]);
    }
}

__global__ __launch_bounds__(256) void moe_gate_aux(
    const float* __restrict__ gacc, float* __restrict__ out)
{
    __shared__ float red[4];
    const int tid = threadIdx.x;
    float v = gacc[256 + tid] * gacc[tid];
    #pragma unroll
    for (int o = 32; o > 0; o >>= 1) v += __shfl_down(v, o, 64);
    if ((tid & 63) == 0) red[tid >> 6] = v;
    __syncthreads();
    if (tid == 0) {
        float tot = red[0] + red[1] + red[2] + red[3];
        const float scale = (64.0f / (4096.0f * 6.0f)) / 4096.0f;
        out[2 * T_TOKENS * TOPK] = 1e-3f * (tot * scale) * 0.25f;
    }
}

extern "C" void kernel_launch(void* const* d_in, const int* in_sizes, int n_in,
                              void* d_out, int out_size, void* d_ws, size_t ws_size,
                              hipStream_t stream) {
    const float* x   = (const float*)d_in[0];
    const float* wgt = (const float*)d_in[1];
    float* out  = (float*)d_out;
    float* gacc = (float*)d_ws;

    hipMemsetAsync(d_ws, 0, 512 * sizeof(float), stream);
    moe_gate_main<<<T_TOKENS / TPB, 1024, 0, stream>>>(x, wgt, out, gacc);
    moe_gate_aux<<<1, 256, 0, stream>>>(gacc, out);
}

// Round 6
// 336.142 us; speedup vs baseline: 9.8245x; 1.1544x over previous
//
#include <hip/hip_runtime.h>
#include <math.h>

// CRITICAL: no FMA contraction anywhere — we are bit-replicating numpy's
// SSE (no-FMA) float32 einsum inner loop.
#pragma clang fp contract(off)

#define T_TOKENS 16384
#define HDIM 2048
#define NEXP 64
#define TOPK 6
#define SEQ 4096
#define TPB 32          // tokens per block
#define KC 64           // k-chunk (floats); W row = X row = 64 floats, UNPADDED
#define NC (HDIM / KC)  // 32 chunks
#define LGS 65          // padded stride for logits
#define PS 65           // padded stride for probs

typedef __attribute__((address_space(1))) const unsigned int gu32;
typedef __attribute__((address_space(3))) unsigned int lu32;

// numpy einsum contig_two micro-step (SSE3 baseline, 4 lanes, no FMA):
// per 16-element block: vacc[l] = a0[l]*b0[l] + (a1[l]*b1[l] + (a2[l]*b2[l] + (a3[l]*b3[l] + vacc[l])))
__device__ __forceinline__ void np_upd(const float4& w0, const float4& w1,
                                       const float4& w2, const float4& w3,
                                       const float4& x0, const float4& x1,
                                       const float4& x2, const float4& x3,
                                       float acc[4])
{
    acc[0] = w0.x*x0.x + (w1.x*x1.x + (w2.x*x2.x + (w3.x*x3.x + acc[0])));
    acc[1] = w0.y*x0.y + (w1.y*x1.y + (w2.y*x2.y + (w3.y*x3.y + acc[1])));
    acc[2] = w0.z*x0.z + (w1.z*x1.z + (w2.z*x2.z + (w3.z*x3.z + acc[2])));
    acc[3] = w0.w*x0.w + (w1.w*x1.w + (w2.w*x2.w + (w3.w*x3.w + acc[3])));
}

// 512 threads = 8 waves; thread = 1 token x 4 experts (R2-verified geometry).
// Staging: 3x global_load_lds per thread per chunk (zero VGPR residency),
// double-buffered, ONE __syncthreads per chunk. Loads for chunk c+1 are
// issued before compute of chunk c; the compiler's vmcnt(0) drain at the
// end-of-chunk barrier lands a full compute phase (~4K cyc) after issue,
// so HBM latency is hidden. Tiles are UNPADDED with source-side XOR swizzle
// (phys 16B slot = logical ^ (row&7)): W-reads 2-way (free), X-reads clean.
__global__ __launch_bounds__(512, 4) void moe_gate_main(
    const float* __restrict__ x, const float* __restrict__ wgt,
    float* __restrict__ out, float* __restrict__ gacc)
{
    __shared__ __attribute__((aligned(16))) float w_lds[2][NEXP * KC];  // 32 KB
    __shared__ __attribute__((aligned(16))) float x_lds[2][TPB * KC];   // 16 KB
    __shared__ float lg[TPB * LGS];        //  8320 B fp32 logits (np bit-exact)
    __shared__ float probs[TPB * PS];      //  8320 B
    __shared__ float psum[8 * NEXP];       //  2048 B
    __shared__ int   cnt[NEXP];            //   256 B   (~67 KB total, 2 blocks/CU)

    const int tid  = threadIdx.x;
    const int bid  = blockIdx.x;
    const int tb   = bid * TPB;
    const int b    = tb / SEQ;

    const int lane = tid & 63;
    const int wv   = tid >> 6;       // 0..7
    const int le   = lane & 15;      // expert sub-index
    const int g    = lane >> 4;      // 0..3
    const int trow = wv * 4 + g;     // token row 0..31

    // ---- staging geometry (source-swizzled, LDS-linear dest = m173 pattern)
    // W: 1024 slots (64 rows x 16), thread handles slots tid and tid+512.
    const int wrow0 = tid >> 4;                  // 0..31 (round 1: +32, same &7)
    const int wp    = tid & 15;
    const int wls   = wp ^ (wrow0 & 7);          // logical slot held at phys slot wp
    const float* wgsrc0 = wgt + (size_t)wrow0 * HDIM + wls * 4;
    const float* wgsrc1 = wgt + (size_t)(wrow0 + 32) * HDIM + wls * 4;
    // X: 512 slots (32 rows x 16), thread handles slot tid.
    const int xrow = tid >> 4;
    const int xls  = (tid & 15) ^ (xrow & 7);
    const float* xgsrc = x + (size_t)(tb + xrow) * HDIM + xls * 4;
    // LDS linear dests: wave-uniform base + lane*16 (m97-verified form)
    char* wdst0 = (char*)&w_lds[0][0] + tid * 16;
    char* wdst1 = wdst0 + 512 * 16;
    char* xdst  = (char*)&x_lds[0][0] + tid * 16;

    float acc[4][4];
    #pragma unroll
    for (int j = 0; j < 4; ++j)
        #pragma unroll
        for (int l = 0; l < 4; ++l) acc[j][l] = 0.f;

    // ---- prologue: stage chunk 0 into buffer 0 (async, reg-free)
    __builtin_amdgcn_global_load_lds((gu32*)wgsrc0, (lu32*)wdst0, 16, 0, 0);
    __builtin_amdgcn_global_load_lds((gu32*)wgsrc1, (lu32*)wdst1, 16, 0, 0);
    __builtin_amdgcn_global_load_lds((gu32*)xgsrc,  (lu32*)xdst,  16, 0, 0);
    __syncthreads();

    const int xswz = trow & 7;   // read-side slot XOR for own token row
    const int wswz = le & 7;     // read-side slot XOR for expert rows (same for all je)

    for (int c = 0; c < NC; ++c) {
        const int cur = c & 1;
        // issue next chunk's staging into the other buffer (in flight under
        // compute; drained by the compiler's vmcnt(0) at the barrier below)
        if (c + 1 < NC) {
            const int k1 = (c + 1) * KC;
            const int bo_w = (cur ^ 1) * (NEXP * KC * 4);
            const int bo_x = (cur ^ 1) * (TPB * KC * 4);
            __builtin_amdgcn_global_load_lds((gu32*)(wgsrc0 + k1), (lu32*)(wdst0 + bo_w), 16, 0, 0);
            __builtin_amdgcn_global_load_lds((gu32*)(wgsrc1 + k1), (lu32*)(wdst1 + bo_w), 16, 0, 0);
            __builtin_amdgcn_global_load_lds((gu32*)(xgsrc  + k1), (lu32*)(xdst  + bo_x), 16, 0, 0);
        }

        // ---- compute chunk c from buf[cur]; k ascending in blocks of 16
        const char* wb = (const char*)&w_lds[cur][0];
        const char* xb = (const char*)&x_lds[cur][0] + trow * 256;
        #pragma unroll
        for (int b16 = 0; b16 < 4; ++b16) {
            float4 xa[4];
            #pragma unroll
            for (int j = 0; j < 4; ++j)
                xa[j] = *(const float4*)(xb + (((b16 * 4 + j) ^ xswz) << 4));
            #pragma unroll
            for (int je = 0; je < 4; ++je) {
                const char* wr = wb + (le + 16 * je) * 256;
                const float4 w0 = *(const float4*)(wr + (((b16 * 4 + 0) ^ wswz) << 4));
                const float4 w1 = *(const float4*)(wr + (((b16 * 4 + 1) ^ wswz) << 4));
                const float4 w2 = *(const float4*)(wr + (((b16 * 4 + 2) ^ wswz) << 4));
                const float4 w3 = *(const float4*)(wr + (((b16 * 4 + 3) ^ wswz) << 4));
                np_upd(w0, w1, w2, w3, xa[0], xa[1], xa[2], xa[3], acc[je]);
            }
        }
        __syncthreads();   // single barrier per chunk
    }

    // horizontal reduce exactly like npyv_sum_f32 (SSE3 hadd): (v0+v1)+(v2+v3)
    #pragma unroll
    for (int je = 0; je < 4; ++je) {
        float v = (acc[je][0] + acc[je][1]) + (acc[je][2] + acc[je][3]);
        lg[trow * LGS + le + 16 * je] = v;
    }
    if (tid < NEXP) cnt[tid] = 0;
    __syncthreads();

    // ---- softmax per token (threads 0..31), fp32 like np
    if (tid < TPB) {
        const int t = tid;
        float mx = lg[t * LGS];
        for (int e = 1; e < NEXP; ++e) { float v = lg[t * LGS + e]; if (v > mx) mx = v; }
        for (int e = 0; e < NEXP; ++e)
            probs[t * PS + e] = expf(lg[t * LGS + e] - mx);
        // numpy pairwise sum, n=64: 8 strided accumulators then paired combine
        float r[8];
        #pragma unroll
        for (int j = 0; j < 8; ++j) r[j] = probs[t * PS + j];
        for (int i = 8; i < 64; i += 8)
            #pragma unroll
            for (int j = 0; j < 8; ++j) r[j] += probs[t * PS + i + j];
        float S = ((r[0] + r[1]) + (r[2] + r[3])) + ((r[4] + r[5]) + (r[6] + r[7]));
        for (int e = 0; e < NEXP; ++e) probs[t * PS + e] = probs[t * PS + e] / S;
    }
    __syncthreads();

    // ---- partial per-expert score sums (aux loss), all 512 threads
    {
        const int e = tid & 63, q = tid >> 6;   // q = 0..7, 4 tokens each
        float s = 0.f;
        for (int t = q * 4; t < q * 4 + 4; ++t) s += probs[t * PS + e];
        psum[q * 64 + e] = s;
    }
    __syncthreads();

    if (tid < TPB) {
        // ---- top-6 on fp32 probs, strict > ascending scan (tie -> lowest index)
        const int t = tid;
        const int gt = tb + t;
        float pv[TOPK]; int pi[TOPK];
        for (int r = 0; r < TOPK; ++r) {
            float bv = -1.f; int be = 0;
            for (int e = 0; e < NEXP; ++e) {
                float v = probs[t * PS + e];
                if (v > bv) { bv = v; be = e; }
            }
            probs[t * PS + be] = -1.f;
            pv[r] = bv; pi[r] = be;
            atomicAdd(&cnt[be], 1);
        }
        float wsum = pv[0];
        #pragma unroll
        for (int r = 1; r < TOPK; ++r) wsum += pv[r];
        wsum += 1e-20f;
        #pragma unroll
        for (int r = 0; r < TOPK; ++r) {
            out[(size_t)gt * TOPK + r] = (float)pi[r];
            out[(size_t)T_TOKENS * TOPK + (size_t)gt * TOPK + r] = pv[r] / wsum;
        }
    } else if (tid >= 64 && tid < 128) {
        const int e = tid - 64;
        float s = 0.f;
        #pragma unroll
        for (int q = 0; q < 8; ++q) s += psum[q * 64 + e];
        atomicAdd(&gacc[b * 64 + e], s);
    }
    __syncthreads();
    if (tid < NEXP) {
        atomicAdd(&gacc[256 + b * 64 + tid], (float)cnt[tid]);
    }
}

__global__ __launch_bounds__(256) void moe_gate_aux(
    const float* __restrict__ gacc, float* __restrict__ out)
{
    __shared__ float red[4];
    const int tid = threadIdx.x;
    float v = gacc[256 + tid] * gacc[tid];
    #pragma unroll
    for (int o = 32; o > 0; o >>= 1) v += __shfl_down(v, o, 64);
    if ((tid & 63) == 0) red[tid >> 6] = v;
    __syncthreads();
    if (tid == 0) {
        float tot = red[0] + red[1] + red[2] + red[3];
        const float scale = (64.0f / (4096.0f * 6.0f)) / 4096.0f;
        out[2 * T_TOKENS * TOPK] = 1e-3f * (tot * scale) * 0.25f;
    }
}

extern "C" void kernel_launch(void* const* d_in, const int* in_sizes, int n_in,
                              void* d_out, int out_size, void* d_ws, size_t ws_size,
                              hipStream_t stream) {
    const float* x   = (const float*)d_in[0];
    const float* wgt = (const float*)d_in[1];
    float* out  = (float*)d_out;
    float* gacc = (float*)d_ws;

    hipMemsetAsync(d_ws, 0, 512 * sizeof(float), stream);
    moe_gate_main<<<T_TOKENS / TPB, 512, 0, stream>>>(x, wgt, out, gacc);
    moe_gate_aux<<<1, 256, 0, stream>>>(gacc, out);
}